// Round 1
// baseline (665.281 us; speedup 1.0000x reference)
//
#include <hip/hip_runtime.h>
#include <math.h>

#define BB 4
#define SS 512
#define PP 128
#define CC 64
#define KK 64
#define NCTX_ 16
#define TT 64
#define NTILES ((BB*SS)/TT)   // 32

// ---------------------------------------------------------------------------
// Kernel 1: per (class, 64-token tile) compute gated GLN prediction b[b,s,c]
// and store it into the outputs region of d_out (scan kernel updates in place).
// ---------------------------------------------------------------------------
__global__ __launch_bounds__(256) void predict_kernel(
    const float* __restrict__ x,
    const float* __restrict__ H1,
    const float* __restrict__ W1,
    const float* __restrict__ H2,
    const float* __restrict__ W2,
    const float* __restrict__ fc2w,
    const float* __restrict__ fc2b,
    float* __restrict__ bout)
{
    __shared__ float xs[PP][TT + 1];    // [p][t], stride 65 -> conflict-free reads
    __shared__ float l1s[TT][KK + 1];   // [t][k], stride 65
    __shared__ float bitss[4][TT];
    __shared__ float apart[4][TT];

    const int tid  = threadIdx.x;
    const int lane = tid & 63;
    const int wid  = __builtin_amdgcn_readfirstlane(tid >> 6);
    const int c    = blockIdx.x >> 5;            // / NTILES
    const int tile = blockIdx.x & (NTILES - 1);
    const int tok0 = tile * TT;

    // ---- stage x tile, transposed into LDS -------------------------------
    {
        const float4* xg = reinterpret_cast<const float4*>(x + (size_t)tok0 * PP);
        #pragma unroll
        for (int it = 0; it < (TT * PP / 4) / 256; ++it) {
            const int i = it * 256 + tid;
            const float4 v = xg[i];
            const int t = i >> 5;          // 32 float4 per token row
            const int p = (i & 31) << 2;
            xs[p + 0][t] = v.x;
            xs[p + 1][t] = v.y;
            xs[p + 2][t] = v.z;
            xs[p + 3][t] = v.w;
        }
    }
    __syncthreads();

    // ---- Phase A: layer-1 halfspace contexts (wave w owns k = w*16+i) ----
    int ctxreg[16];
    {
        const float* H1c = H1 + (size_t)c * KK * 4 * PP;
        #pragma unroll
        for (int i = 0; i < 16; ++i) {
            const int k = wid * 16 + i;
            const float* h = H1c + (size_t)k * 4 * PP;   // wave-uniform
            float d0 = 0.f, d1 = 0.f, d2 = 0.f, d3 = 0.f;
            #pragma unroll 8
            for (int p = 0; p < PP; ++p) {
                const float xv = xs[p][lane];
                d0 = fmaf(h[p],          xv, d0);
                d1 = fmaf(h[PP + p],     xv, d1);
                d2 = fmaf(h[2 * PP + p], xv, d2);
                d3 = fmaf(h[3 * PP + p], xv, d3);
            }
            ctxreg[i] = (d0 > 0.f ? 1 : 0) | (d1 > 0.f ? 2 : 0) |
                        (d2 > 0.f ? 4 : 0) | (d3 > 0.f ? 8 : 0);
        }
    }

    // ---- Phase A2: output-layer context bit (one j per wave) + alpha partial
    {
        const float* h2 = H2 + ((size_t)c * 4 + wid) * PP;
        float d = 0.f;
        #pragma unroll 8
        for (int p = 0; p < PP; ++p) d = fmaf(h2[p], xs[p][lane], d);
        bitss[wid][lane] = (d > 0.f) ? 1.f : 0.f;

        const float* fw = fc2w + (size_t)c * PP;
        float ap = 0.f;
        #pragma unroll 8
        for (int p = wid * 32; p < wid * 32 + 32; ++p)
            ap = fmaf(fw[p], xs[p][lane], ap);
        apart[wid][lane] = ap;
    }
    __syncthreads();

    // ---- clip x in place -> l0 (base predictions in logit space) ---------
    for (int i = tid; i < PP * TT; i += 256) {
        const int p = i >> 6, t = i & 63;
        xs[p][t] = fminf(fmaxf(xs[p][t], -5.f), 5.f);
    }
    __syncthreads();

    // ---- Phase B: gated geometric mixing, layer 1 ------------------------
    {
        const float* W1c = W1 + (size_t)c * KK * NCTX_ * PP;
        #pragma unroll
        for (int i = 0; i < 16; ++i) {
            const int k = wid * 16 + i;
            const float* w = W1c + ((size_t)(k * NCTX_ + ctxreg[i])) * PP; // per-lane ctx
            const float4* w4 = reinterpret_cast<const float4*>(w);
            float acc = 0.f;
            #pragma unroll 4
            for (int p4 = 0; p4 < PP / 4; ++p4) {
                const float4 wv = w4[p4];
                acc = fmaf(wv.x, xs[4 * p4 + 0][lane], acc);
                acc = fmaf(wv.y, xs[4 * p4 + 1][lane], acc);
                acc = fmaf(wv.z, xs[4 * p4 + 2][lane], acc);
                acc = fmaf(wv.w, xs[4 * p4 + 3][lane], acc);
            }
            l1s[lane][k] = fminf(fmaxf(acc, -5.f), 5.f);
        }
    }
    __syncthreads();

    // ---- Phase C: output neuron + multihead gate + store (wave 0) --------
    if (wid == 0) {
        const int t = lane;
        const int ctx2 = (bitss[0][t] > 0.5f ? 1 : 0) | (bitss[1][t] > 0.5f ? 2 : 0) |
                         (bitss[2][t] > 0.5f ? 4 : 0) | (bitss[3][t] > 0.5f ? 8 : 0);
        const float* w2 = W2 + ((size_t)c * NCTX_ + ctx2) * KK;
        float l2 = 0.f;
        #pragma unroll 8
        for (int k = 0; k < KK; ++k) l2 = fmaf(w2[k], l1s[t][k], l2);
        const float alpha = apart[0][t] + apart[1][t] + apart[2][t] + apart[3][t] + fc2b[c];
        const float bv = (1.f / (1.f + expf(-l2))) * (1.f / (1.f + expf(-alpha)));
        const int tok = tok0 + t;
        bout[(size_t)tok * CC + c] = bv;
    }
}

// ---------------------------------------------------------------------------
// Kernel 2: sequential roll+add+relu scan over S, in place over d_out.
// One wave per batch, lane = class. roll(h,1): lane c reads lane c-1.
// ---------------------------------------------------------------------------
__global__ __launch_bounds__(64) void scan_kernel(const float* __restrict__ hidden,
                                                  float* __restrict__ out)
{
    const int b    = blockIdx.x;
    const int lane = threadIdx.x;
    const int src  = (lane + 63) & 63;     // lane - 1 mod 64
    float h = hidden[b * CC + lane];
    float* row = out + (size_t)b * SS * CC;
    #pragma unroll 4
    for (int s = 0; s < SS; ++s) {
        const float bv   = row[s * CC + lane];
        const float prev = __shfl(h, src, 64);
        h = fmaxf(bv + prev, 0.f);
        row[s * CC + lane] = h;
    }
    out[(size_t)BB * SS * CC + b * CC + lane] = h;   // h_last
}

extern "C" void kernel_launch(void* const* d_in, const int* in_sizes, int n_in,
                              void* d_out, int out_size, void* d_ws, size_t ws_size,
                              hipStream_t stream) {
    const float* x      = (const float*)d_in[0];
    const float* hidden = (const float*)d_in[1];
    const float* H1     = (const float*)d_in[2];
    const float* W1     = (const float*)d_in[3];
    const float* H2     = (const float*)d_in[4];
    const float* W2     = (const float*)d_in[5];
    const float* fc2w   = (const float*)d_in[6];
    const float* fc2b   = (const float*)d_in[7];
    float* out = (float*)d_out;

    predict_kernel<<<dim3(CC * NTILES), 256, 0, stream>>>(x, H1, W1, H2, W2, fc2w, fc2b, out);
    scan_kernel<<<dim3(BB), 64, 0, stream>>>(hidden, out);
}

// Round 2
// 456.356 us; speedup vs baseline: 1.4578x; 1.4578x over previous
//
#include <hip/hip_runtime.h>
#include <math.h>

#define BB 4
#define SS 512
#define PP 128
#define CC 64
#define KK 64
#define NCTX_ 16
#define TT 64
#define NTILES ((BB*SS)/TT)   // 32

// ---------------------------------------------------------------------------
// Repack W1 (c,k,ctx,p) -> (c,k,p4,ctx) as float4, so Phase B gathers for the
// 64 lanes of a wave land in a 256B window (<=4 cache lines per instruction)
// instead of 64 distinct 512B rows.
// One wave per (c,k) tile: 16x128 floats = 512 float4.
// ---------------------------------------------------------------------------
__global__ __launch_bounds__(256) void repack_kernel(const float* __restrict__ W1,
                                                     float* __restrict__ W1r)
{
    __shared__ float4 ls[4][16][32];
    const int lane = threadIdx.x & 63;
    const int w    = threadIdx.x >> 6;
    const int tile = blockIdx.x * 4 + w;          // c*64 + k
    const float4* in4  = reinterpret_cast<const float4*>(W1) + (size_t)tile * 512;
    float4*       out4 = reinterpret_cast<float4*>(W1r)      + (size_t)tile * 512;
    #pragma unroll
    for (int it = 0; it < 8; ++it) {
        const int i = it * 64 + lane;             // i = ctx*32 + p4
        ls[w][i >> 5][i & 31] = in4[i];
    }
    __syncthreads();
    #pragma unroll
    for (int it = 0; it < 8; ++it) {
        const int o = it * 64 + lane;             // o = p4*16 + ctx
        out4[o] = ls[w][o & 15][o >> 4];
    }
}

// ---------------------------------------------------------------------------
// Kernel 1: per (class, 64-token tile) compute gated GLN prediction b[b,s,c].
// CSTRIDE/PSTRIDE are float4 strides into the W1 buffer:
//   repacked: idx = (c*64+k)*512 + p4*16 + ctx   (CSTRIDE=1,  PSTRIDE=16)
//   original: idx = (c*64+k)*512 + ctx*32 + p4   (CSTRIDE=32, PSTRIDE=1)
// ---------------------------------------------------------------------------
template <int CSTRIDE, int PSTRIDE>
__global__ __launch_bounds__(256, 4) void predict_kernel(
    const float* __restrict__ x,
    const float* __restrict__ H1,
    const float* __restrict__ W1b,
    const float* __restrict__ H2,
    const float* __restrict__ W2,
    const float* __restrict__ fc2w,
    const float* __restrict__ fc2b,
    float* __restrict__ bout)
{
    __shared__ float xs[PP][TT + 1];    // [p][t], stride 65 -> conflict-free
    __shared__ float bitss[4][TT];
    __shared__ float apart[4][TT];
    __shared__ float l2part[4][TT];

    const int tid  = threadIdx.x;
    const int lane = tid & 63;
    const int wid  = __builtin_amdgcn_readfirstlane(tid >> 6);
    // XCD-aware swizzle: 2048 blocks = 8 XCD * 256; each XCD gets 8 classes
    // -> its 4MB L2 holds exactly those classes' W1 slices.
    const int bid  = blockIdx.x;
    const int sw   = ((bid & 7) << 8) | (bid >> 3);
    const int c    = sw >> 5;
    const int tile = sw & (NTILES - 1);
    const int tok0 = tile * TT;

    // ---- stage x tile, transposed into LDS -------------------------------
    {
        const float4* xg = reinterpret_cast<const float4*>(x + (size_t)tok0 * PP);
        #pragma unroll
        for (int it = 0; it < (TT * PP / 4) / 256; ++it) {
            const int i = it * 256 + tid;
            const float4 v = xg[i];
            const int t = i >> 5;
            const int p = (i & 31) << 2;
            xs[p + 0][t] = v.x;
            xs[p + 1][t] = v.y;
            xs[p + 2][t] = v.z;
            xs[p + 3][t] = v.w;
        }
    }
    __syncthreads();

    // ---- Phase A: layer-1 halfspace contexts; 2 neurons per x-read -------
    int ctxreg[16];
    {
        const float* H1c = H1 + (size_t)c * KK * 4 * PP;
        #pragma unroll
        for (int i = 0; i < 16; i += 2) {
            const int k = wid * 16 + i;
            const float* ha = H1c + (size_t)k * 4 * PP;   // wave-uniform -> SGPR
            const float* hb = ha + 4 * PP;
            float a0 = 0.f, a1 = 0.f, a2 = 0.f, a3 = 0.f;
            float b0 = 0.f, b1 = 0.f, b2 = 0.f, b3 = 0.f;
            #pragma unroll 4
            for (int p = 0; p < PP; ++p) {
                const float xv = xs[p][lane];
                a0 = fmaf(ha[p],          xv, a0);
                a1 = fmaf(ha[PP + p],     xv, a1);
                a2 = fmaf(ha[2 * PP + p], xv, a2);
                a3 = fmaf(ha[3 * PP + p], xv, a3);
                b0 = fmaf(hb[p],          xv, b0);
                b1 = fmaf(hb[PP + p],     xv, b1);
                b2 = fmaf(hb[2 * PP + p], xv, b2);
                b3 = fmaf(hb[3 * PP + p], xv, b3);
            }
            ctxreg[i]     = (a0 > 0.f ? 1 : 0) | (a1 > 0.f ? 2 : 0) |
                            (a2 > 0.f ? 4 : 0) | (a3 > 0.f ? 8 : 0);
            ctxreg[i + 1] = (b0 > 0.f ? 1 : 0) | (b1 > 0.f ? 2 : 0) |
                            (b2 > 0.f ? 4 : 0) | (b3 > 0.f ? 8 : 0);
        }
    }

    // ---- Phase A2: output-layer context bit + alpha partial --------------
    {
        const float* h2 = H2 + ((size_t)c * 4 + wid) * PP;
        float d = 0.f;
        #pragma unroll 8
        for (int p = 0; p < PP; ++p) d = fmaf(h2[p], xs[p][lane], d);
        bitss[wid][lane] = (d > 0.f) ? 1.f : 0.f;

        const float* fw = fc2w + (size_t)c * PP;
        float ap = 0.f;
        #pragma unroll 8
        for (int p = wid * 32; p < wid * 32 + 32; ++p)
            ap = fmaf(fw[p], xs[p][lane], ap);
        apart[wid][lane] = ap;
    }
    __syncthreads();

    // ---- clip x in place -> l0 -------------------------------------------
    for (int i = tid; i < PP * TT; i += 256) {
        const int p = i >> 6, t = i & 63;
        xs[p][t] = fminf(fmaxf(xs[p][t], -5.f), 5.f);
    }
    __syncthreads();

    // ---- Phase B: gated geometric mixing; 8 neurons per x-read -----------
    float l1v[16];
    {
        const float4* W1c4 = reinterpret_cast<const float4*>(W1b) +
                             (size_t)(c * KK + wid * 16) * 512;
        #pragma unroll
        for (int g = 0; g < 2; ++g) {
            float s[8] = {0.f, 0.f, 0.f, 0.f, 0.f, 0.f, 0.f, 0.f};
            const float4* wp[8];
            #pragma unroll
            for (int j = 0; j < 8; ++j) {
                const int kk = g * 8 + j;
                wp[j] = W1c4 + (size_t)kk * 512 + (size_t)ctxreg[kk] * CSTRIDE;
            }
            #pragma unroll 2
            for (int p4 = 0; p4 < 32; ++p4) {
                const float x0 = xs[4 * p4 + 0][lane];
                const float x1 = xs[4 * p4 + 1][lane];
                const float x2 = xs[4 * p4 + 2][lane];
                const float x3 = xs[4 * p4 + 3][lane];
                #pragma unroll
                for (int j = 0; j < 8; ++j) {
                    const float4 wv = wp[j][p4 * PSTRIDE];   // compile-time offset
                    s[j] = fmaf(wv.w, x3, fmaf(wv.z, x2,
                           fmaf(wv.y, x1, fmaf(wv.x, x0, s[j]))));
                }
            }
            #pragma unroll
            for (int j = 0; j < 8; ++j)
                l1v[g * 8 + j] = fminf(fmaxf(s[j], -5.f), 5.f);
        }
    }

    // ---- Phase C: per-wave partial of output neuron ----------------------
    {
        const int ctx2 = (bitss[0][lane] > 0.5f ? 1 : 0) | (bitss[1][lane] > 0.5f ? 2 : 0) |
                         (bitss[2][lane] > 0.5f ? 4 : 0) | (bitss[3][lane] > 0.5f ? 8 : 0);
        const float* w2 = W2 + ((size_t)c * NCTX_ + ctx2) * KK + wid * 16;
        float lp = 0.f;
        #pragma unroll
        for (int j = 0; j < 16; ++j) lp = fmaf(w2[j], l1v[j], lp);
        l2part[wid][lane] = lp;
    }
    __syncthreads();

    if (wid == 0) {
        const int t = lane;
        const float l2 = (l2part[0][t] + l2part[1][t]) + (l2part[2][t] + l2part[3][t]);
        const float alpha = apart[0][t] + apart[1][t] + apart[2][t] + apart[3][t] + fc2b[c];
        const float bv = (1.f / (1.f + expf(-l2))) * (1.f / (1.f + expf(-alpha)));
        bout[(size_t)(tok0 + t) * CC + c] = bv;
    }
}

// ---------------------------------------------------------------------------
// Kernel 2: sequential roll+add+relu scan, depth-8 software pipeline so the
// 512 serial L2-latency loads overlap (one stall per 8 steps instead of 512).
// ---------------------------------------------------------------------------
__global__ __launch_bounds__(64) void scan_kernel(const float* __restrict__ hidden,
                                                  float* __restrict__ out)
{
    const int b    = blockIdx.x;
    const int lane = threadIdx.x;
    const int src  = (lane + 63) & 63;     // lane - 1 mod 64
    float h = hidden[b * CC + lane];
    float* row = out + (size_t)b * SS * CC;

    float c[8], n[8];
    #pragma unroll
    for (int j = 0; j < 8; ++j) c[j] = row[j * CC + lane];

    for (int s = 0; s < SS; s += 8) {
        if (s + 8 < SS) {
            #pragma unroll
            for (int j = 0; j < 8; ++j) n[j] = row[(s + 8 + j) * CC + lane];
        }
        #pragma unroll
        for (int j = 0; j < 8; ++j) {
            const float prev = __shfl(h, src, 64);
            h = fmaxf(c[j] + prev, 0.f);
            row[(s + j) * CC + lane] = h;
        }
        #pragma unroll
        for (int j = 0; j < 8; ++j) c[j] = n[j];
    }
    out[(size_t)BB * SS * CC + b * CC + lane] = h;   // h_last
}

extern "C" void kernel_launch(void* const* d_in, const int* in_sizes, int n_in,
                              void* d_out, int out_size, void* d_ws, size_t ws_size,
                              hipStream_t stream) {
    const float* x      = (const float*)d_in[0];
    const float* hidden = (const float*)d_in[1];
    const float* H1     = (const float*)d_in[2];
    const float* W1     = (const float*)d_in[3];
    const float* H2     = (const float*)d_in[4];
    const float* W2     = (const float*)d_in[5];
    const float* fc2w   = (const float*)d_in[6];
    const float* fc2b   = (const float*)d_in[7];
    float* out = (float*)d_out;

    const size_t w1_bytes = (size_t)CC * KK * NCTX_ * PP * sizeof(float);
    if (ws_size >= w1_bytes) {
        float* W1r = (float*)d_ws;
        repack_kernel<<<dim3(CC * KK / 4), 256, 0, stream>>>(W1, W1r);
        predict_kernel<1, 16><<<dim3(CC * NTILES), 256, 0, stream>>>(
            x, H1, W1r, H2, W2, fc2w, fc2b, out);
    } else {
        predict_kernel<32, 1><<<dim3(CC * NTILES), 256, 0, stream>>>(
            x, H1, W1, H2, W2, fc2w, fc2b, out);
    }
    scan_kernel<<<dim3(BB), 64, 0, stream>>>(hidden, out);
}

// Round 3
// 342.996 us; speedup vs baseline: 1.9396x; 1.3305x over previous
//
#include <hip/hip_runtime.h>
#include <math.h>

#define BB 4
#define SS 512
#define PP 128
#define CC 64
#define KK 64
#define NCTX_ 16
#define TT 64
#define NTILES ((BB*SS)/TT)   // 32

// ---------------------------------------------------------------------------
// Repack W1 (c,k,ctx,p) -> (c,k,p4,ctx) as float4, so Phase B gathers for the
// 64 lanes of a wave land in a 256B window (<=4 cache lines per instruction).
// ---------------------------------------------------------------------------
__global__ __launch_bounds__(256) void repack_kernel(const float* __restrict__ W1,
                                                     float* __restrict__ W1r)
{
    __shared__ float4 ls[4][16][32];
    const int lane = threadIdx.x & 63;
    const int w    = threadIdx.x >> 6;
    const int tile = blockIdx.x * 4 + w;          // c*64 + k
    const float4* in4  = reinterpret_cast<const float4*>(W1) + (size_t)tile * 512;
    float4*       out4 = reinterpret_cast<float4*>(W1r)      + (size_t)tile * 512;
    #pragma unroll
    for (int it = 0; it < 8; ++it) {
        const int i = it * 64 + lane;             // i = ctx*32 + p4
        ls[w][i >> 5][i & 31] = in4[i];
    }
    __syncthreads();
    #pragma unroll
    for (int it = 0; it < 8; ++it) {
        const int o = it * 64 + lane;             // o = p4*16 + ctx
        out4[o] = ls[w][o & 15][o >> 4];
    }
}

// ---------------------------------------------------------------------------
// Kernel 1: per (class, 64-token tile) compute gated GLN prediction b[b,s,c].
//   repacked W1: idx = (c*64+k)*512 + p4*16 + ctx   (CSTRIDE=1,  PSTRIDE=16)
//   original W1: idx = (c*64+k)*512 + ctx*32 + p4   (CSTRIDE=32, PSTRIDE=1)
// ---------------------------------------------------------------------------
template <int CSTRIDE, int PSTRIDE>
__global__ __launch_bounds__(256, 4) void predict_kernel(
    const float* __restrict__ x,
    const float* __restrict__ H1,
    const float* __restrict__ W1b,
    const float* __restrict__ H2,
    const float* __restrict__ W2,
    const float* __restrict__ fc2w,
    const float* __restrict__ fc2b,
    float* __restrict__ bout)
{
    __shared__ float xs[PP][TT + 1];    // [p][t], stride 65
    __shared__ float bitss[4][TT];
    __shared__ float apart[4][TT];
    __shared__ float l2part[4][TT];

    const int tid  = threadIdx.x;
    const int lane = tid & 63;
    const int wid  = __builtin_amdgcn_readfirstlane(tid >> 6);
    // XCD-aware swizzle: 2048 blocks = 8 XCD * 256; each XCD gets 8 classes.
    const int bid  = blockIdx.x;
    const int sw   = ((bid & 7) << 8) | (bid >> 3);
    const int c    = sw >> 5;
    const int tile = sw & (NTILES - 1);
    const int tok0 = tile * TT;

    // ---- stage x tile, transposed into LDS -------------------------------
    {
        const float4* xg = reinterpret_cast<const float4*>(x + (size_t)tok0 * PP);
        #pragma unroll
        for (int it = 0; it < (TT * PP / 4) / 256; ++it) {
            const int i = it * 256 + tid;
            const float4 v = xg[i];
            const int t = i >> 5;
            const int p = (i & 31) << 2;
            xs[p + 0][t] = v.x;
            xs[p + 1][t] = v.y;
            xs[p + 2][t] = v.z;
            xs[p + 3][t] = v.w;
        }
    }
    __syncthreads();

    // ---- Phase A: layer-1 halfspace contexts; 2 neurons (8 rows) per group,
    //      float4 weight loads: 8 loads per 32 FMAs (was 8 loads per 8 FMAs).
    int ctxreg[16];
    {
        const float4* H1c4 = reinterpret_cast<const float4*>(
            H1 + (size_t)c * KK * 4 * PP);
        #pragma unroll
        for (int g = 0; g < 8; ++g) {
            const int k = wid * 16 + g * 2;
            const float4* h4 = H1c4 + (size_t)k * 4 * 32;   // 8 rows x 32 float4
            float acc[8] = {0.f, 0.f, 0.f, 0.f, 0.f, 0.f, 0.f, 0.f};
            #pragma unroll 2
            for (int p4 = 0; p4 < 32; ++p4) {
                const float x0 = xs[4 * p4 + 0][lane];
                const float x1 = xs[4 * p4 + 1][lane];
                const float x2 = xs[4 * p4 + 2][lane];
                const float x3 = xs[4 * p4 + 3][lane];
                #pragma unroll
                for (int r = 0; r < 8; ++r) {
                    const float4 w = h4[r * 32 + p4];
                    acc[r] = fmaf(w.w, x3, fmaf(w.z, x2,
                             fmaf(w.y, x1, fmaf(w.x, x0, acc[r]))));
                }
            }
            ctxreg[g * 2]     = (acc[0] > 0.f ? 1 : 0) | (acc[1] > 0.f ? 2 : 0) |
                                (acc[2] > 0.f ? 4 : 0) | (acc[3] > 0.f ? 8 : 0);
            ctxreg[g * 2 + 1] = (acc[4] > 0.f ? 1 : 0) | (acc[5] > 0.f ? 2 : 0) |
                                (acc[6] > 0.f ? 4 : 0) | (acc[7] > 0.f ? 8 : 0);
        }
    }

    // ---- Phase A2: output-layer context bit + alpha partial (float4) -----
    {
        const float4* h2 = reinterpret_cast<const float4*>(
            H2 + ((size_t)c * 4 + wid) * PP);
        float d = 0.f;
        #pragma unroll 8
        for (int p4 = 0; p4 < 32; ++p4) {
            const float4 w = h2[p4];
            d = fmaf(w.w, xs[4 * p4 + 3][lane], fmaf(w.z, xs[4 * p4 + 2][lane],
                fmaf(w.y, xs[4 * p4 + 1][lane], fmaf(w.x, xs[4 * p4 + 0][lane], d))));
        }
        bitss[wid][lane] = (d > 0.f) ? 1.f : 0.f;

        const float4* fw = reinterpret_cast<const float4*>(fc2w + (size_t)c * PP) + wid * 8;
        float ap = 0.f;
        #pragma unroll
        for (int p4 = 0; p4 < 8; ++p4) {
            const float4 w = fw[p4];
            const int p = wid * 32 + 4 * p4;
            ap = fmaf(w.w, xs[p + 3][lane], fmaf(w.z, xs[p + 2][lane],
                 fmaf(w.y, xs[p + 1][lane], fmaf(w.x, xs[p + 0][lane], ap))));
        }
        apart[wid][lane] = ap;
    }
    __syncthreads();

    // ---- clip x in place -> l0 -------------------------------------------
    for (int i = tid; i < PP * TT; i += 256) {
        const int p = i >> 6, t = i & 63;
        xs[p][t] = fminf(fmaxf(xs[p][t], -5.f), 5.f);
    }
    __syncthreads();

    // ---- Phase B: gated geometric mixing; 8 neurons per x-read -----------
    float l1v[16];
    {
        const float4* W1c4 = reinterpret_cast<const float4*>(W1b) +
                             (size_t)(c * KK + wid * 16) * 512;
        #pragma unroll
        for (int g = 0; g < 2; ++g) {
            float s[8] = {0.f, 0.f, 0.f, 0.f, 0.f, 0.f, 0.f, 0.f};
            const float4* wp[8];
            #pragma unroll
            for (int j = 0; j < 8; ++j) {
                const int kk = g * 8 + j;
                wp[j] = W1c4 + (size_t)kk * 512 + (size_t)ctxreg[kk] * CSTRIDE;
            }
            #pragma unroll 2
            for (int p4 = 0; p4 < 32; ++p4) {
                const float x0 = xs[4 * p4 + 0][lane];
                const float x1 = xs[4 * p4 + 1][lane];
                const float x2 = xs[4 * p4 + 2][lane];
                const float x3 = xs[4 * p4 + 3][lane];
                #pragma unroll
                for (int j = 0; j < 8; ++j) {
                    const float4 wv = wp[j][p4 * PSTRIDE];
                    s[j] = fmaf(wv.w, x3, fmaf(wv.z, x2,
                           fmaf(wv.y, x1, fmaf(wv.x, x0, s[j]))));
                }
            }
            #pragma unroll
            for (int j = 0; j < 8; ++j)
                l1v[g * 8 + j] = fminf(fmaxf(s[j], -5.f), 5.f);
        }
    }

    // ---- Phase C: per-wave partial of output neuron ----------------------
    {
        const int ctx2 = (bitss[0][lane] > 0.5f ? 1 : 0) | (bitss[1][lane] > 0.5f ? 2 : 0) |
                         (bitss[2][lane] > 0.5f ? 4 : 0) | (bitss[3][lane] > 0.5f ? 8 : 0);
        const float* w2 = W2 + ((size_t)c * NCTX_ + ctx2) * KK + wid * 16;
        float lp = 0.f;
        #pragma unroll
        for (int j = 0; j < 16; ++j) lp = fmaf(w2[j], l1v[j], lp);
        l2part[wid][lane] = lp;
    }
    __syncthreads();

    if (wid == 0) {
        const int t = lane;
        const float l2 = (l2part[0][t] + l2part[1][t]) + (l2part[2][t] + l2part[3][t]);
        const float alpha = apart[0][t] + apart[1][t] + apart[2][t] + apart[3][t] + fc2b[c];
        const float bv = (1.f / (1.f + expf(-l2))) * (1.f / (1.f + expf(-alpha)));
        bout[(size_t)(tok0 + t) * CC + c] = bv;
    }
}

// ---------------------------------------------------------------------------
// Kernel 2: sequential roll+add+relu scan, depth-8 software pipeline.
// ---------------------------------------------------------------------------
__global__ __launch_bounds__(64) void scan_kernel(const float* __restrict__ hidden,
                                                  float* __restrict__ out)
{
    const int b    = blockIdx.x;
    const int lane = threadIdx.x;
    const int src  = (lane + 63) & 63;     // lane - 1 mod 64
    float h = hidden[b * CC + lane];
    float* row = out + (size_t)b * SS * CC;

    float c[8], n[8];
    #pragma unroll
    for (int j = 0; j < 8; ++j) c[j] = row[j * CC + lane];

    for (int s = 0; s < SS; s += 8) {
        if (s + 8 < SS) {
            #pragma unroll
            for (int j = 0; j < 8; ++j) n[j] = row[(s + 8 + j) * CC + lane];
        }
        #pragma unroll
        for (int j = 0; j < 8; ++j) {
            const float prev = __shfl(h, src, 64);
            h = fmaxf(c[j] + prev, 0.f);
            row[(s + j) * CC + lane] = h;
        }
        #pragma unroll
        for (int j = 0; j < 8; ++j) c[j] = n[j];
    }
    out[(size_t)BB * SS * CC + b * CC + lane] = h;   // h_last
}

extern "C" void kernel_launch(void* const* d_in, const int* in_sizes, int n_in,
                              void* d_out, int out_size, void* d_ws, size_t ws_size,
                              hipStream_t stream) {
    const float* x      = (const float*)d_in[0];
    const float* hidden = (const float*)d_in[1];
    const float* H1     = (const float*)d_in[2];
    const float* W1     = (const float*)d_in[3];
    const float* H2     = (const float*)d_in[4];
    const float* W2     = (const float*)d_in[5];
    const float* fc2w   = (const float*)d_in[6];
    const float* fc2b   = (const float*)d_in[7];
    float* out = (float*)d_out;

    const size_t w1_bytes = (size_t)CC * KK * NCTX_ * PP * sizeof(float);
    if (ws_size >= w1_bytes) {
        float* W1r = (float*)d_ws;
        repack_kernel<<<dim3(CC * KK / 4), 256, 0, stream>>>(W1, W1r);
        predict_kernel<1, 16><<<dim3(CC * NTILES), 256, 0, stream>>>(
            x, H1, W1r, H2, W2, fc2w, fc2b, out);
    } else {
        predict_kernel<32, 1><<<dim3(CC * NTILES), 256, 0, stream>>>(
            x, H1, W1, H2, W2, fc2w, fc2b, out);
    }
    scan_kernel<<<dim3(BB), 64, 0, stream>>>(hidden, out);
}

// Round 4
// 272.089 us; speedup vs baseline: 2.4451x; 1.2606x over previous
//
#include <hip/hip_runtime.h>
#include <math.h>

#define BB 4
#define SS 512
#define PP 128
#define CC 64
#define KK 64
#define NCTX_ 16
#define TT 64
#define NTILES ((BB*SS)/TT)   // 32

typedef __attribute__((ext_vector_type(8))) short bf16x8;
typedef __attribute__((ext_vector_type(4))) float f32x4;

static __device__ __forceinline__ float bf2f(short h) {
    unsigned u = ((unsigned)(unsigned short)h) << 16;
    return __builtin_bit_cast(float, u);
}
static __device__ __forceinline__ short f2bf(float f) {
    unsigned u = __builtin_bit_cast(unsigned, f);
    unsigned r = (u + 0x7fffu + ((u >> 16) & 1u)) >> 16;
    return (short)(unsigned short)r;
}

// ---------------------------------------------------------------------------
// Repack W1 (c,k,ctx,p) -> (c,k,p4,ctx) as float4 (Phase B gather locality).
// ---------------------------------------------------------------------------
__global__ __launch_bounds__(256) void repack_kernel(const float* __restrict__ W1,
                                                     float* __restrict__ W1r)
{
    __shared__ float4 ls[4][16][32];
    const int lane = threadIdx.x & 63;
    const int w    = threadIdx.x >> 6;
    const int tile = blockIdx.x * 4 + w;          // c*64 + k
    const float4* in4  = reinterpret_cast<const float4*>(W1) + (size_t)tile * 512;
    float4*       out4 = reinterpret_cast<float4*>(W1r)      + (size_t)tile * 512;
    #pragma unroll
    for (int it = 0; it < 8; ++it) {
        const int i = it * 64 + lane;             // i = ctx*32 + p4
        ls[w][i >> 5][i & 31] = in4[i];
    }
    __syncthreads();
    #pragma unroll
    for (int it = 0; it < 8; ++it) {
        const int o = it * 64 + lane;             // o = p4*16 + ctx
        out4[o] = ls[w][o & 15][o >> 4];
    }
}

// ---------------------------------------------------------------------------
// Split H1 (16384 rows x 128 f32) into bf16 hi/lo planes (row-major, same order)
// ---------------------------------------------------------------------------
__global__ __launch_bounds__(256) void h1split_kernel(const float* __restrict__ H1,
                                                      short* __restrict__ H1h,
                                                      short* __restrict__ H1l)
{
    const size_t i4 = ((size_t)blockIdx.x * 256 + threadIdx.x) * 4;
    const float4 v = *reinterpret_cast<const float4*>(H1 + i4);
    short4 h, l;
    h.x = f2bf(v.x); l.x = f2bf(v.x - bf2f(h.x));
    h.y = f2bf(v.y); l.y = f2bf(v.y - bf2f(h.y));
    h.z = f2bf(v.z); l.z = f2bf(v.z - bf2f(h.z));
    h.w = f2bf(v.w); l.w = f2bf(v.w - bf2f(h.w));
    *reinterpret_cast<short4*>(H1h + i4) = h;
    *reinterpret_cast<short4*>(H1l + i4) = l;
}

// ---------------------------------------------------------------------------
// Kernel 1: per (class, 64-token tile) gated GLN prediction b[b,s,c].
//   W1 strides (float4): repacked CSTRIDE=1,PSTRIDE=16; original 32,1.
//   MFMA=true: layer-1 contexts via split-bf16 3-pass 16x16x32 MFMA.
// ---------------------------------------------------------------------------
template <int CSTRIDE, int PSTRIDE, bool MFMA>
__global__ __launch_bounds__(256, 4) void predict_kernel(
    const float* __restrict__ x,
    const float* __restrict__ H1,
    const short* __restrict__ H1h,
    const short* __restrict__ H1l,
    const float* __restrict__ W1b,
    const float* __restrict__ H2,
    const float* __restrict__ W2,
    const float* __restrict__ fc2w,
    const float* __restrict__ fc2b,
    float* __restrict__ bout)
{
    __shared__ float xs[PP][TT + 1];    // [p][t], stride 65 -> conflict-free
    __shared__ float bitss[4][TT];
    __shared__ float apart[4][TT];
    __shared__ float l2part[4][TT];

    const int tid  = threadIdx.x;
    const int lane = tid & 63;
    const int wid  = __builtin_amdgcn_readfirstlane(tid >> 6);
    // XCD-aware swizzle: 2048 blocks = 8 XCD * 256; each XCD gets 8 classes.
    const int bid  = blockIdx.x;
    const int sw   = ((bid & 7) << 8) | (bid >> 3);
    const int c    = sw >> 5;
    const int tile = sw & (NTILES - 1);
    const int tok0 = tile * TT;

    // ---- stage x tile, transposed into LDS (raw f32) ---------------------
    {
        const float4* xg = reinterpret_cast<const float4*>(x + (size_t)tok0 * PP);
        #pragma unroll
        for (int it = 0; it < (TT * PP / 4) / 256; ++it) {
            const int i = it * 256 + tid;
            const float4 v = xg[i];
            const int t = i >> 5;
            const int p = (i & 31) << 2;
            xs[p + 0][t] = v.x;
            xs[p + 1][t] = v.y;
            xs[p + 2][t] = v.z;
            xs[p + 3][t] = v.w;
        }
    }
    __syncthreads();

    int ctxreg[16];

    if constexpr (MFMA) {
        // ---- Phase A (MFMA): D[n][tok] = H1[n,:]·x[tok,:], sign -> ctx bits.
        // A = H1 rows (hi/lo bf16 from global), B = x (built from LDS f32).
        // D layout: col = lane&15 = token, row = 4*(lane>>4)+r = n-in-tile.
        // n = wid*64 + nt*16 + 4g + r  =>  k = wid*16 + nt*4 + g, j = r:
        // all 4 j-bits of (tok,k) live in ONE lane's 4 acc regs.
        __shared__ unsigned char ctxb[TT][68];
        const int t15 = lane & 15;
        const int g   = lane >> 4;
        const int g8  = g * 8;
        const size_t rowbase = (size_t)c * 256 + (size_t)wid * 64;
        const f32x4 zero4 = {0.f, 0.f, 0.f, 0.f};

        #pragma unroll
        for (int half = 0; half < 2; ++half) {
            f32x4 acc[4][2];
            #pragma unroll
            for (int nt = 0; nt < 4; ++nt) {
                acc[nt][0] = zero4;
                acc[nt][1] = zero4;
            }
            #pragma unroll
            for (int q = 0; q < 4; ++q) {
                // build B-frags (x hi/lo) for the 2 token-tiles of this half
                bf16x8 bh[2], bl[2];
                #pragma unroll
                for (int j2 = 0; j2 < 2; ++j2) {
                    const int tok = (half * 2 + j2) * 16 + t15;
                    float xv[8];
                    #pragma unroll
                    for (int e = 0; e < 8; ++e) xv[e] = xs[q * 32 + g8 + e][tok];
                    bf16x8 hb, lb;
                    #pragma unroll
                    for (int e = 0; e < 8; ++e) {
                        const short h = f2bf(xv[e]);
                        hb[e] = h;
                        lb[e] = f2bf(xv[e] - bf2f(h));
                    }
                    bh[j2] = hb; bl[j2] = lb;
                }
                #pragma unroll
                for (int nt = 0; nt < 4; ++nt) {
                    const size_t rn = (rowbase + (size_t)(nt * 16 + t15)) * PP + q * 32 + g8;
                    const bf16x8 ah = *reinterpret_cast<const bf16x8*>(H1h + rn);
                    const bf16x8 al = *reinterpret_cast<const bf16x8*>(H1l + rn);
                    #pragma unroll
                    for (int j2 = 0; j2 < 2; ++j2) {
                        acc[nt][j2] = __builtin_amdgcn_mfma_f32_16x16x32_bf16(ah, bh[j2], acc[nt][j2], 0, 0, 0);
                        acc[nt][j2] = __builtin_amdgcn_mfma_f32_16x16x32_bf16(ah, bl[j2], acc[nt][j2], 0, 0, 0);
                        acc[nt][j2] = __builtin_amdgcn_mfma_f32_16x16x32_bf16(al, bh[j2], acc[nt][j2], 0, 0, 0);
                    }
                }
            }
            // extract ctx nibbles (in-lane) and drop into LDS
            #pragma unroll
            for (int nt = 0; nt < 4; ++nt) {
                #pragma unroll
                for (int j2 = 0; j2 < 2; ++j2) {
                    const int tok = (half * 2 + j2) * 16 + t15;
                    const int k   = wid * 16 + nt * 4 + g;
                    const int cv  = (acc[nt][j2][0] > 0.f ? 1 : 0) |
                                    (acc[nt][j2][1] > 0.f ? 2 : 0) |
                                    (acc[nt][j2][2] > 0.f ? 4 : 0) |
                                    (acc[nt][j2][3] > 0.f ? 8 : 0);
                    ctxb[tok][k] = (unsigned char)cv;
                }
            }
        }
        // wave reads only its own k-range (written by itself) -> no barrier needed
        #pragma unroll
        for (int i = 0; i < 16; ++i) ctxreg[i] = ctxb[lane][wid * 16 + i];
    } else {
        // ---- Phase A (VALU fallback): 2 neurons (8 rows) per group, float4.
        const float4* H1c4 = reinterpret_cast<const float4*>(
            H1 + (size_t)c * KK * 4 * PP);
        #pragma unroll
        for (int gg = 0; gg < 8; ++gg) {
            const int k = wid * 16 + gg * 2;
            const float4* h4 = H1c4 + (size_t)k * 4 * 32;
            float acc[8] = {0.f, 0.f, 0.f, 0.f, 0.f, 0.f, 0.f, 0.f};
            #pragma unroll 2
            for (int p4 = 0; p4 < 32; ++p4) {
                const float x0 = xs[4 * p4 + 0][lane];
                const float x1 = xs[4 * p4 + 1][lane];
                const float x2 = xs[4 * p4 + 2][lane];
                const float x3 = xs[4 * p4 + 3][lane];
                #pragma unroll
                for (int r = 0; r < 8; ++r) {
                    const float4 w = h4[r * 32 + p4];
                    acc[r] = fmaf(w.w, x3, fmaf(w.z, x2,
                             fmaf(w.y, x1, fmaf(w.x, x0, acc[r]))));
                }
            }
            ctxreg[gg * 2]     = (acc[0] > 0.f ? 1 : 0) | (acc[1] > 0.f ? 2 : 0) |
                                 (acc[2] > 0.f ? 4 : 0) | (acc[3] > 0.f ? 8 : 0);
            ctxreg[gg * 2 + 1] = (acc[4] > 0.f ? 1 : 0) | (acc[5] > 0.f ? 2 : 0) |
                                 (acc[6] > 0.f ? 4 : 0) | (acc[7] > 0.f ? 8 : 0);
        }
    }

    // ---- Phase A2: output-layer context bit + alpha partial (float4) -----
    {
        const float4* h2 = reinterpret_cast<const float4*>(
            H2 + ((size_t)c * 4 + wid) * PP);
        float d = 0.f;
        #pragma unroll 8
        for (int p4 = 0; p4 < 32; ++p4) {
            const float4 w = h2[p4];
            d = fmaf(w.w, xs[4 * p4 + 3][lane], fmaf(w.z, xs[4 * p4 + 2][lane],
                fmaf(w.y, xs[4 * p4 + 1][lane], fmaf(w.x, xs[4 * p4 + 0][lane], d))));
        }
        bitss[wid][lane] = (d > 0.f) ? 1.f : 0.f;

        const float4* fw = reinterpret_cast<const float4*>(fc2w + (size_t)c * PP) + wid * 8;
        float ap = 0.f;
        #pragma unroll
        for (int p4 = 0; p4 < 8; ++p4) {
            const float4 w = fw[p4];
            const int p = wid * 32 + 4 * p4;
            ap = fmaf(w.w, xs[p + 3][lane], fmaf(w.z, xs[p + 2][lane],
                 fmaf(w.y, xs[p + 1][lane], fmaf(w.x, xs[p + 0][lane], ap))));
        }
        apart[wid][lane] = ap;
    }
    __syncthreads();

    // ---- clip x in place -> l0 -------------------------------------------
    for (int i = tid; i < PP * TT; i += 256) {
        const int p = i >> 6, t = i & 63;
        xs[p][t] = fminf(fmaxf(xs[p][t], -5.f), 5.f);
    }
    __syncthreads();

    // ---- Phase B: gated geometric mixing; 8 neurons per x-read -----------
    float l1v[16];
    {
        const float4* W1c4 = reinterpret_cast<const float4*>(W1b) +
                             (size_t)(c * KK + wid * 16) * 512;
        #pragma unroll
        for (int gg = 0; gg < 2; ++gg) {
            float s[8] = {0.f, 0.f, 0.f, 0.f, 0.f, 0.f, 0.f, 0.f};
            const float4* wp[8];
            #pragma unroll
            for (int j = 0; j < 8; ++j) {
                const int kk = gg * 8 + j;
                wp[j] = W1c4 + (size_t)kk * 512 + (size_t)ctxreg[kk] * CSTRIDE;
            }
            #pragma unroll 2
            for (int p4 = 0; p4 < 32; ++p4) {
                const float x0 = xs[4 * p4 + 0][lane];
                const float x1 = xs[4 * p4 + 1][lane];
                const float x2 = xs[4 * p4 + 2][lane];
                const float x3 = xs[4 * p4 + 3][lane];
                #pragma unroll
                for (int j = 0; j < 8; ++j) {
                    const float4 wv = wp[j][p4 * PSTRIDE];
                    s[j] = fmaf(wv.w, x3, fmaf(wv.z, x2,
                           fmaf(wv.y, x1, fmaf(wv.x, x0, s[j]))));
                }
            }
            #pragma unroll
            for (int j = 0; j < 8; ++j)
                l1v[gg * 8 + j] = fminf(fmaxf(s[j], -5.f), 5.f);
        }
    }

    // ---- Phase C: per-wave partial of output neuron ----------------------
    {
        const int ctx2 = (bitss[0][lane] > 0.5f ? 1 : 0) | (bitss[1][lane] > 0.5f ? 2 : 0) |
                         (bitss[2][lane] > 0.5f ? 4 : 0) | (bitss[3][lane] > 0.5f ? 8 : 0);
        const float* w2 = W2 + ((size_t)c * NCTX_ + ctx2) * KK + wid * 16;
        float lp = 0.f;
        #pragma unroll
        for (int j = 0; j < 16; ++j) lp = fmaf(w2[j], l1v[j], lp);
        l2part[wid][lane] = lp;
    }
    __syncthreads();

    if (wid == 0) {
        const int t = lane;
        const float l2 = (l2part[0][t] + l2part[1][t]) + (l2part[2][t] + l2part[3][t]);
        const float alpha = apart[0][t] + apart[1][t] + apart[2][t] + apart[3][t] + fc2b[c];
        const float bv = (1.f / (1.f + expf(-l2))) * (1.f / (1.f + expf(-alpha)));
        bout[(size_t)(tok0 + t) * CC + c] = bv;
    }
}

// ---------------------------------------------------------------------------
// Kernel 2: sequential roll+add+relu scan, depth-8 software pipeline.
// ---------------------------------------------------------------------------
__global__ __launch_bounds__(64) void scan_kernel(const float* __restrict__ hidden,
                                                  float* __restrict__ out)
{
    const int b    = blockIdx.x;
    const int lane = threadIdx.x;
    const int src  = (lane + 63) & 63;     // lane - 1 mod 64
    float h = hidden[b * CC + lane];
    float* row = out + (size_t)b * SS * CC;

    float c[8], n[8];
    #pragma unroll
    for (int j = 0; j < 8; ++j) c[j] = row[j * CC + lane];

    for (int s = 0; s < SS; s += 8) {
        if (s + 8 < SS) {
            #pragma unroll
            for (int j = 0; j < 8; ++j) n[j] = row[(s + 8 + j) * CC + lane];
        }
        #pragma unroll
        for (int j = 0; j < 8; ++j) {
            const float prev = __shfl(h, src, 64);
            h = fmaxf(c[j] + prev, 0.f);
            row[(s + j) * CC + lane] = h;
        }
        #pragma unroll
        for (int j = 0; j < 8; ++j) c[j] = n[j];
    }
    out[(size_t)BB * SS * CC + b * CC + lane] = h;   // h_last
}

extern "C" void kernel_launch(void* const* d_in, const int* in_sizes, int n_in,
                              void* d_out, int out_size, void* d_ws, size_t ws_size,
                              hipStream_t stream) {
    const float* x      = (const float*)d_in[0];
    const float* hidden = (const float*)d_in[1];
    const float* H1     = (const float*)d_in[2];
    const float* W1     = (const float*)d_in[3];
    const float* H2     = (const float*)d_in[4];
    const float* W2     = (const float*)d_in[5];
    const float* fc2w   = (const float*)d_in[6];
    const float* fc2b   = (const float*)d_in[7];
    float* out = (float*)d_out;

    const size_t MB = 1024 * 1024;
    const size_t w1_bytes = (size_t)CC * KK * NCTX_ * PP * sizeof(float);   // 32 MB
    const size_t h1_elems = (size_t)CC * KK * 4 * PP;                        // 2M

    if (ws_size >= 40 * MB) {
        float* W1r = (float*)d_ws;
        short* H1h = (short*)((char*)d_ws + 32 * MB);
        short* H1l = (short*)((char*)d_ws + 36 * MB);
        repack_kernel<<<dim3(CC * KK / 4), 256, 0, stream>>>(W1, W1r);
        h1split_kernel<<<dim3(h1_elems / 4 / 256), 256, 0, stream>>>(H1, H1h, H1l);
        predict_kernel<1, 16, true><<<dim3(CC * NTILES), 256, 0, stream>>>(
            x, H1, H1h, H1l, W1r, H2, W2, fc2w, fc2b, out);
    } else if (ws_size >= w1_bytes) {
        float* W1r = (float*)d_ws;
        repack_kernel<<<dim3(CC * KK / 4), 256, 0, stream>>>(W1, W1r);
        predict_kernel<1, 16, false><<<dim3(CC * NTILES), 256, 0, stream>>>(
            x, H1, nullptr, nullptr, W1r, H2, W2, fc2w, fc2b, out);
    } else {
        predict_kernel<32, 1, false><<<dim3(CC * NTILES), 256, 0, stream>>>(
            x, H1, nullptr, nullptr, W1, H2, W2, fc2w, fc2b, out);
    }
    scan_kernel<<<dim3(BB), 64, 0, stream>>>(hidden, out);
}